// Round 16
// baseline (326.690 us; speedup 1.0000x reference)
//
#include <hip/hip_runtime.h>

#define OBS 128
#define HID 64
#define ACT 32
#define TT  128
#define BB  4096

typedef __attribute__((ext_vector_type(8))) short bf16x8;  // 8 bf16 (4 VGPRs)
typedef __attribute__((ext_vector_type(4))) float f32x4;

// tanh(v) = 1 - 2/(exp(2v)+1); exact at +-inf, ~1e-6 rel error (v_exp + v_rcp)
__device__ __forceinline__ float fast_tanh(float v) {
  const float e = __expf(2.0f * v);
  return 1.0f - 2.0f * __builtin_amdgcn_rcpf(e + 1.0f);
}

// f32 -> bf16 bits, round-to-nearest-even (prep + capture paths)
__device__ __forceinline__ short f2bf(float f) {
  const unsigned u = __float_as_uint(f);
  return (short)((u + 0x7FFFu + ((u >> 16) & 1u)) >> 16);
}

// HW packed f32x2 -> bf16x2 (RNE), gfx950; no builtin -> inline asm (T12/m240).
__device__ __forceinline__ unsigned cvtpk(float lo, float hi) {
  unsigned r;
  asm("v_cvt_pk_bf16_f32 %0, %1, %2" : "=v"(r) : "v"(lo), "v"(hi));
  return r;
}

// pack two f32x4 (C/D-layout quads) into one bf16x8 B-fragment (4 instrs)
__device__ __forceinline__ bf16x8 cvt8(const f32x4 s0, const f32x4 s1) {
  union { bf16x8 f; unsigned u[4]; } z;
  z.u[0] = cvtpk(s0[0], s0[1]); z.u[1] = cvtpk(s0[2], s0[3]);
  z.u[2] = cvtpk(s1[0], s1[1]); z.u[3] = cvtpk(s1[2], s1[3]);
  return z.f;
}

// pack [float4, float4] -> bf16x8 (a-fragment)
__device__ __forceinline__ bf16x8 cvt8f(const float4 lo, const float4 hi) {
  union { bf16x8 f; unsigned u[4]; } z;
  z.u[0] = cvtpk(lo.x, lo.y); z.u[1] = cvtpk(lo.z, lo.w);
  z.u[2] = cvtpk(hi.x, hi.y); z.u[3] = cvtpk(hi.z, hi.w);
  return z.f;
}

// ---------------------------------------------------------------------------
// Prep: fragment-ordered bf16 weight table in d_ws (capture uses frags 0..23;
// recur gathers its weights directly once at kernel start).
// ---------------------------------------------------------------------------
__global__ void prep_weights(const float* __restrict__ Wc1,
                             const float* __restrict__ Wc2,
                             const float* __restrict__ Wp1,
                             const float* __restrict__ Wp2,
                             short* __restrict__ ws)
{
  const int idx = blockIdx.x * blockDim.x + threadIdx.x;  // 0..(44*64-1)
  if (idx >= 44 * 64) return;
  const int f = idx >> 6, lane = idx & 63;
  const int r = lane & 15, G = lane >> 4;
  short o[8];
  if (f < 16) {
    const int m = f >> 2, kk = f & 3;  // std: k = 32kk + 8G + j
#pragma unroll
    for (int j = 0; j < 8; ++j)
      o[j] = f2bf(Wc1[(kk * 32 + 8 * G + j) * HID + 16 * m + r]);
  } else if (f < 40) {
    const int q = (f < 24) ? (f - 16) : (f < 32) ? (f - 24) : (f - 32);
    const float* W = (f < 24) ? Wc2 : (f < 32) ? Wp1 : Wp2;
    const int m = q >> 1, kk = q & 1;  // custom k-map (matches lane-resident C/D)
#pragma unroll
    for (int j = 0; j < 8; ++j) {
      const int k = (j < 4) ? (32 * kk + 4 * G + j)
                            : (32 * kk + 16 + 4 * G + (j - 4));
      o[j] = f2bf(W[k * HID + 16 * m + r]);
    }
  } else {
    const int m = f - 40;  // a-part, std map: k = HID + 8G + j
#pragma unroll
    for (int j = 0; j < 8; ++j)
      o[j] = f2bf(Wp1[(HID + 8 * G + j) * HID + 16 * m + r]);
  }
  bf16x8 v;
#pragma unroll
  for (int j = 0; j < 8; ++j) v[j] = o[j];
  *(bf16x8*)(ws + (size_t)idx * 8) = v;
}

// ---------------------------------------------------------------------------
// Phase 1: capture — BYTE-IDENTICAL to rounds 9/12/14/15 (deterministic LDS-
// weight form, HBM-bound ~65-75 us at 2 blocks/CU).
// ---------------------------------------------------------------------------
__global__ __launch_bounds__(256, 2) void capture_lds(
    const float* __restrict__ x,
    const short* __restrict__ wsw,
    const float* __restrict__ bc1, const float* __restrict__ bc2,
    float* __restrict__ capt)
{
  __shared__ bf16x8 wl[24 * 64];  // 24.5 KB fragment table

  const int tid  = threadIdx.x;
  const int lane = tid & 63;
  const int r    = lane & 15;   // tile-row (N dim)
  const int G    = lane >> 4;   // k-group
  const int wave = blockIdx.x * 4 + (tid >> 6);
  const int nwaves = gridDim.x * 4;

  // stage fragment table (coalesced 16 B/thread x 6 iters)
  for (int s = tid; s < 24 * 64; s += 256)
    wl[s] = ((const bf16x8*)wsw)[s];
  __syncthreads();

  f32x4 bias1[4], bias2[4];
#pragma unroll
  for (int m = 0; m < 4; ++m) {
    bias1[m] = *(const f32x4*)(bc1 + 16 * m + 4 * G);
    bias2[m] = *(const f32x4*)(bc2 + 16 * m + 4 * G);
  }

  for (int tile = wave; tile < (TT * BB) / 16; tile += nwaves) {
    // structural fence: weight ds_reads cannot be hoisted/CSE'd across
    // iterations -> per-iter LDS reads, deterministic codegen
    asm volatile("" ::: "memory");

    const float* xrow = x + ((size_t)tile * 16 + r) * OBS;
    bf16x8 xa[4];
#pragma unroll
    for (int kk = 0; kk < 4; ++kk) {
      const float4 lo = *(const float4*)(xrow + kk * 32 + 8 * G);
      const float4 hi = *(const float4*)(xrow + kk * 32 + 8 * G + 4);
      bf16x8 f;
      f[0] = f2bf(lo.x); f[1] = f2bf(lo.y); f[2] = f2bf(lo.z); f[3] = f2bf(lo.w);
      f[4] = f2bf(hi.x); f[5] = f2bf(hi.y); f[6] = f2bf(hi.z); f[7] = f2bf(hi.w);
      xa[kk] = f;
    }

    float um[4][4];
#pragma unroll
    for (int m = 0; m < 4; ++m) {
      f32x4 acc = bias1[m];
#pragma unroll
      for (int kk = 0; kk < 4; ++kk)
        acc = __builtin_amdgcn_mfma_f32_16x16x32_bf16(wl[(m * 4 + kk) * 64 + lane],
                                                      xa[kk], acc, 0, 0, 0);
#pragma unroll
      for (int q = 0; q < 4; ++q) um[m][q] = fast_tanh(acc[q]);
    }

    bf16x8 b2[2];
#pragma unroll
    for (int kk = 0; kk < 2; ++kk) {
      bf16x8 f;
#pragma unroll
      for (int j = 0; j < 4; ++j) f[j]     = f2bf(um[2 * kk][j]);
#pragma unroll
      for (int j = 0; j < 4; ++j) f[4 + j] = f2bf(um[2 * kk + 1][j]);
      b2[kk] = f;
    }

    float* crow = capt + ((size_t)tile * 16 + r) * HID;
#pragma unroll
    for (int m = 0; m < 4; ++m) {
      f32x4 acc = bias2[m];
#pragma unroll
      for (int kk = 0; kk < 2; ++kk)
        acc = __builtin_amdgcn_mfma_f32_16x16x32_bf16(wl[(16 + m * 2 + kk) * 64 + lane],
                                                      b2[kk], acc, 0, 0, 0);
      float4 o;
      o.x = fast_tanh(acc[0]); o.y = fast_tanh(acc[1]);
      o.z = fast_tanh(acc[2]); o.w = fast_tanh(acc[3]);
      *(float4*)(crow + 16 * m + 4 * G) = o;
    }
  }
}

// ---------------------------------------------------------------------------
// Phase 2: recurrence — 2-TILE INTERLEAVED monolith (new this round).
// r4 vs r14: same source, same VGPR=120, 77 vs 157 us — the schedule of the
// load/wait placement is a compile lottery when the wave has only ONE serial
// dependency chain. Fix: each wave owns TWO independent batch tiles (A,B) and
// alternates  loadA' -> computeA -> loadB' -> computeB  every step. Chain B's
// ~700 cyc of compute sits structurally between A's load issue and A's load
// use (and vice versa) — latency coverage the scheduler cannot destroy,
// because the independence is dataflow, not schedule. Weights shared by both
// tiles, in-loop-pinned (r15). cvt_pk packing (r12). Zero barriers, no LDS.
// Grid: 128 blocks x 64 threads; wall = per-wave-pair critical path.
// ---------------------------------------------------------------------------
#define R_LOADS(t, ROW, Z0, Z1, Z2, Z3, AL, AH, GV)                 \
  do {                                                              \
    const size_t rb = (size_t)(t) * BB + (ROW);                     \
    const float* zp = z1buf + rb * HID;                             \
    Z0 = *(const f32x4*)(zp + 4 * G);                               \
    Z1 = *(const f32x4*)(zp + 16 + 4 * G);                          \
    Z2 = *(const f32x4*)(zp + 32 + 4 * G);                          \
    Z3 = *(const f32x4*)(zp + 48 + 4 * G);                          \
    const float* ap = a + rb * ACT + 8 * G;                         \
    AL = *(const float4*)(ap);                                      \
    AH = *(const float4*)(ap + 4);                                  \
    GV = g[rb];                                                     \
  } while (0)

#define R_COMPUTE(t, ROW, HB0, HB1, Z0, Z1, Z2, Z3, AL, AH, GV)                \
  do {                                                                         \
    const bf16x8 ab = cvt8f(AL, AH);                                           \
    f32x4 um[4];                                                               \
    _Pragma("unroll")                                                          \
    for (int m = 0; m < 4; ++m) {                                              \
      f32x4 acc = bias1[m];                                                    \
      acc = __builtin_amdgcn_mfma_f32_16x16x32_bf16(w1h[m][0], HB0, acc, 0, 0, 0); \
      acc = __builtin_amdgcn_mfma_f32_16x16x32_bf16(w1h[m][1], HB1, acc, 0, 0, 0); \
      acc = __builtin_amdgcn_mfma_f32_16x16x32_bf16(w1a[m], ab, acc, 0, 0, 0); \
      f32x4 u;                                                                 \
      u[0] = fast_tanh(acc[0]); u[1] = fast_tanh(acc[1]);                      \
      u[2] = fast_tanh(acc[2]); u[3] = fast_tanh(acc[3]);                      \
      um[m] = u;                                                               \
    }                                                                          \
    const bf16x8 ub0 = cvt8(um[0], um[1]);                                     \
    const bf16x8 ub1 = cvt8(um[2], um[3]);                                     \
    const size_t ob = ((size_t)(t) * BB + (ROW)) * HID;                        \
    f32x4 hm[4];                                                               \
    _Pragma("unroll")                                                          \
    for (int m = 0; m < 4; ++m) {                                              \
      f32x4 acc = bias2[m];                                                    \
      acc = __builtin_amdgcn_mfma_f32_16x16x32_bf16(w2t[m][0], ub0, acc, 0, 0, 0); \
      acc = __builtin_amdgcn_mfma_f32_16x16x32_bf16(w2t[m][1], ub1, acc, 0, 0, 0); \
      const f32x4 zz = (m == 0) ? Z0 : (m == 1) ? Z1 : (m == 2) ? Z2 : Z3;     \
      f32x4 hn;                                                                \
      hn[0] = fmaf(GV, fast_tanh(acc[0]) - zz[0], zz[0]);                      \
      hn[1] = fmaf(GV, fast_tanh(acc[1]) - zz[1], zz[1]);                      \
      hn[2] = fmaf(GV, fast_tanh(acc[2]) - zz[2], zz[2]);                      \
      hn[3] = fmaf(GV, fast_tanh(acc[3]) - zz[3], zz[3]);                      \
      hm[m] = hn;                                                              \
      *(f32x4*)(outs + ob + 16 * m + 4 * G) = hn;                              \
    }                                                                          \
    HB0 = cvt8(hm[0], hm[1]);                                                  \
    HB1 = cvt8(hm[2], hm[3]);                                                  \
  } while (0)

__global__ __launch_bounds__(64, 1) void recur_mfma2t(
    const float* __restrict__ h0,
    const float* __restrict__ g,
    const float* __restrict__ a,
    const float* __restrict__ Wp1, const float* __restrict__ bp1,
    const float* __restrict__ Wp2, const float* __restrict__ bp2,
    const float* __restrict__ z1buf,
    float* __restrict__ outs, float* __restrict__ hlast)
{
  const int lane = threadIdx.x & 63;
  const int r    = lane & 15;
  const int G    = lane >> 4;
  const int rowA = (blockIdx.x * 2) * 16 + r;      // tile A row
  const int rowB = (blockIdx.x * 2 + 1) * 16 + r;  // tile B row

  // ---- weight fragments: gathered once, shared by both tiles ----
  bf16x8 w1h[4][2], w2t[4][2], w1a[4];
#pragma unroll
  for (int m = 0; m < 4; ++m) {
#pragma unroll
    for (int kk = 0; kk < 2; ++kk) {
      bf16x8 f1, f2;
#pragma unroll
      for (int j = 0; j < 8; ++j) {
        const int k = (j < 4) ? (32 * kk + 4 * G + j)
                              : (32 * kk + 16 + 4 * G + (j - 4));
        f1[j] = f2bf(Wp1[k * HID + 16 * m + r]);
        f2[j] = f2bf(Wp2[k * HID + 16 * m + r]);
      }
      w1h[m][kk] = f1;
      w2t[m][kk] = f2;
    }
    bf16x8 fa;  // a-part, standard map: k = HID + 8G + j
#pragma unroll
    for (int j = 0; j < 8; ++j)
      fa[j] = f2bf(Wp1[(HID + 8 * G + j) * HID + 16 * m + r]);
    w1a[m] = fa;
  }
  f32x4 bias1[4], bias2[4];
#pragma unroll
  for (int m = 0; m < 4; ++m) {
    bias1[m] = *(const f32x4*)(bp1 + 16 * m + 4 * G);
    bias2[m] = *(const f32x4*)(bp2 + 16 * m + 4 * G);
  }

  // ---- h state (bf16 fragments only; f32 h is step-local) ----
  bf16x8 hbA0, hbA1, hbB0, hbB1;
  {
    f32x4 t0 = *(const f32x4*)(h0 + (size_t)rowA * HID + 4 * G);
    f32x4 t1 = *(const f32x4*)(h0 + (size_t)rowA * HID + 16 + 4 * G);
    f32x4 t2 = *(const f32x4*)(h0 + (size_t)rowA * HID + 32 + 4 * G);
    f32x4 t3 = *(const f32x4*)(h0 + (size_t)rowA * HID + 48 + 4 * G);
    hbA0 = cvt8(t0, t1); hbA1 = cvt8(t2, t3);
    t0 = *(const f32x4*)(h0 + (size_t)rowB * HID + 4 * G);
    t1 = *(const f32x4*)(h0 + (size_t)rowB * HID + 16 + 4 * G);
    t2 = *(const f32x4*)(h0 + (size_t)rowB * HID + 32 + 4 * G);
    t3 = *(const f32x4*)(h0 + (size_t)rowB * HID + 48 + 4 * G);
    hbB0 = cvt8(t0, t1); hbB1 = cvt8(t2, t3);
  }

  // ---- double-buffered step inputs, per tile ----
  f32x4 zA00, zA01, zA02, zA03, zA10, zA11, zA12, zA13;  // tile A, phase 0/1
  f32x4 zB00, zB01, zB02, zB03, zB10, zB11, zB12, zB13;  // tile B, phase 0/1
  float4 aA0l, aA0h, aA1l, aA1h, aB0l, aB0h, aB1l, aB1h;
  float gA0, gA1, gB0, gB1;

  R_LOADS(0, rowA, zA00, zA01, zA02, zA03, aA0l, aA0h, gA0);
  R_LOADS(0, rowB, zB00, zB01, zB02, zB03, aB0l, aB0h, gB0);

  for (int t = 0; t < TT; t += 2) {
    // in-loop pin: weights/biases are loop-carried opaque values (r15)
#pragma unroll
    for (int m = 0; m < 4; ++m) {
      asm volatile("" : "+v"(w1h[m][0]), "+v"(w1h[m][1]));
      asm volatile("" : "+v"(w2t[m][0]), "+v"(w2t[m][1]));
      asm volatile("" : "+v"(w1a[m]));
      asm volatile("" : "+v"(bias1[m]), "+v"(bias2[m]));
    }

    const int t2 = (t + 2 < TT) ? (t + 2) : (TT - 1);  // clamp (redundant reload)

    // step t: consume phase0, prefetch t+1 into phase1
    R_LOADS(t + 1, rowA, zA10, zA11, zA12, zA13, aA1l, aA1h, gA1);
    R_COMPUTE(t, rowA, hbA0, hbA1, zA00, zA01, zA02, zA03, aA0l, aA0h, gA0);
    R_LOADS(t + 1, rowB, zB10, zB11, zB12, zB13, aB1l, aB1h, gB1);
    R_COMPUTE(t, rowB, hbB0, hbB1, zB00, zB01, zB02, zB03, aB0l, aB0h, gB0);

    // step t+1: consume phase1, prefetch t+2 into phase0
    R_LOADS(t2, rowA, zA00, zA01, zA02, zA03, aA0l, aA0h, gA0);
    R_COMPUTE(t + 1, rowA, hbA0, hbA1, zA10, zA11, zA12, zA13, aA1l, aA1h, gA1);
    R_LOADS(t2, rowB, zB00, zB01, zB02, zB03, aB0l, aB0h, gB0);
    R_COMPUTE(t + 1, rowB, hbB0, hbB1, zB10, zB11, zB12, zB13, aB1l, aB1h, gB1);
  }

  // ---- hlast: unpack final bf16 h fragments back to f32 via MFMA-free path:
  // recompute from last outs store is wasteful; instead store the f32 h kept
  // in the last R_COMPUTE. Simplest correct path: reload the last outs row.
  // outs[T-1] was just written by this wave (same addresses) — read back.
  {
    const size_t obA = ((size_t)(TT - 1) * BB + rowA) * HID;
    const size_t obB = ((size_t)(TT - 1) * BB + rowB) * HID;
#pragma unroll
    for (int m = 0; m < 4; ++m) {
      *(f32x4*)(hlast + (size_t)rowA * HID + 16 * m + 4 * G) =
          *(const f32x4*)(outs + obA + 16 * m + 4 * G);
      *(f32x4*)(hlast + (size_t)rowB * HID + 16 * m + 4 * G) =
          *(const f32x4*)(outs + obB + 16 * m + 4 * G);
    }
  }
}

extern "C" void kernel_launch(void* const* d_in, const int* in_sizes, int n_in,
                              void* d_out, int out_size, void* d_ws, size_t ws_size,
                              hipStream_t stream) {
  const float* x   = (const float*)d_in[0];
  const float* h0  = (const float*)d_in[1];
  const float* g   = (const float*)d_in[2];
  const float* a   = (const float*)d_in[3];
  const float* Wc1 = (const float*)d_in[4];
  const float* bc1 = (const float*)d_in[5];
  const float* Wc2 = (const float*)d_in[6];
  const float* bc2 = (const float*)d_in[7];
  const float* Wp1 = (const float*)d_in[8];
  const float* bp1 = (const float*)d_in[9];
  const float* Wp2 = (const float*)d_in[10];
  const float* bp2 = (const float*)d_in[11];

  float* out   = (float*)d_out;
  float* outs  = out;                                   // [T,B,H]
  float* hlast = out + (size_t)TT * BB * HID;           // [1,B,H]
  float* capt  = hlast + (size_t)BB * HID;              // [T,B,H]
  short* wsw   = (short*)d_ws;                          // 44 KB fragment buffer

  prep_weights<<<dim3(11), dim3(256), 0, stream>>>(Wc1, Wc2, Wp1, Wp2, wsw);
  capture_lds<<<dim3(2048), dim3(256), 0, stream>>>(x, wsw, bc1, bc2, capt);
  recur_mfma2t<<<dim3(BB / 32), dim3(64), 0, stream>>>(h0, g, a, Wp1, bp1, Wp2, bp2,
                                                       capt, outs, hlast);
}

// Round 17
// 203.747 us; speedup vs baseline: 1.6034x; 1.6034x over previous
//
#include <hip/hip_runtime.h>

#define OBS 128
#define HID 64
#define ACT 32
#define TT  128
#define BB  4096

typedef __attribute__((ext_vector_type(8))) short bf16x8;  // 8 bf16 (4 VGPRs)
typedef __attribute__((ext_vector_type(4))) float f32x4;

// tanh(v) = 1 - 2/(exp(2v)+1); exact at +-inf, ~1e-6 rel error (v_exp + v_rcp)
__device__ __forceinline__ float fast_tanh(float v) {
  const float e = __expf(2.0f * v);
  return 1.0f - 2.0f * __builtin_amdgcn_rcpf(e + 1.0f);
}

// f32 -> bf16 bits, round-to-nearest-even (prep + capture paths)
__device__ __forceinline__ short f2bf(float f) {
  const unsigned u = __float_as_uint(f);
  return (short)((u + 0x7FFFu + ((u >> 16) & 1u)) >> 16);
}

// HW packed f32x2 -> bf16x2 (RNE), gfx950; no builtin -> inline asm (T12/m240).
__device__ __forceinline__ unsigned cvtpk(float lo, float hi) {
  unsigned r;
  asm("v_cvt_pk_bf16_f32 %0, %1, %2" : "=v"(r) : "v"(lo), "v"(hi));
  return r;
}

// pack two f32x4 (C/D-layout quads) into one bf16x8 B-fragment (4 instrs)
__device__ __forceinline__ bf16x8 cvt8(const f32x4 s0, const f32x4 s1) {
  union { bf16x8 f; unsigned u[4]; } z;
  z.u[0] = cvtpk(s0[0], s0[1]); z.u[1] = cvtpk(s0[2], s0[3]);
  z.u[2] = cvtpk(s1[0], s1[1]); z.u[3] = cvtpk(s1[2], s1[3]);
  return z.f;
}

// pack [float4, float4] -> bf16x8 (a-fragment)
__device__ __forceinline__ bf16x8 cvt8f(const float4 lo, const float4 hi) {
  union { bf16x8 f; unsigned u[4]; } z;
  z.u[0] = cvtpk(lo.x, lo.y); z.u[1] = cvtpk(lo.z, lo.w);
  z.u[2] = cvtpk(hi.x, hi.y); z.u[3] = cvtpk(hi.z, hi.w);
  return z.f;
}

// LDS barrier: drain own ds ops, sync waves (NOT __syncthreads — no vmcnt drain)
__device__ __forceinline__ void lds_barrier() {
  asm volatile("s_waitcnt lgkmcnt(0)" ::: "memory");
  __builtin_amdgcn_s_barrier();
  asm volatile("" ::: "memory");
}

// ---------------------------------------------------------------------------
// Prep: fragment-ordered bf16 weight table in d_ws (capture uses frags 0..23).
// ---------------------------------------------------------------------------
__global__ void prep_weights(const float* __restrict__ Wc1,
                             const float* __restrict__ Wc2,
                             const float* __restrict__ Wp1,
                             const float* __restrict__ Wp2,
                             short* __restrict__ ws)
{
  const int idx = blockIdx.x * blockDim.x + threadIdx.x;  // 0..(44*64-1)
  if (idx >= 44 * 64) return;
  const int f = idx >> 6, lane = idx & 63;
  const int r = lane & 15, G = lane >> 4;
  short o[8];
  if (f < 16) {
    const int m = f >> 2, kk = f & 3;  // std: k = 32kk + 8G + j
#pragma unroll
    for (int j = 0; j < 8; ++j)
      o[j] = f2bf(Wc1[(kk * 32 + 8 * G + j) * HID + 16 * m + r]);
  } else if (f < 40) {
    const int q = (f < 24) ? (f - 16) : (f < 32) ? (f - 24) : (f - 32);
    const float* W = (f < 24) ? Wc2 : (f < 32) ? Wp1 : Wp2;
    const int m = q >> 1, kk = q & 1;  // custom k-map (matches lane-resident C/D)
#pragma unroll
    for (int j = 0; j < 8; ++j) {
      const int k = (j < 4) ? (32 * kk + 4 * G + j)
                            : (32 * kk + 16 + 4 * G + (j - 4));
      o[j] = f2bf(W[k * HID + 16 * m + r]);
    }
  } else {
    const int m = f - 40;  // a-part, std map: k = HID + 8G + j
#pragma unroll
    for (int j = 0; j < 8; ++j)
      o[j] = f2bf(Wp1[(HID + 8 * G + j) * HID + 16 * m + r]);
  }
  bf16x8 v;
#pragma unroll
  for (int j = 0; j < 8; ++j) v[j] = o[j];
  *(bf16x8*)(ws + (size_t)idx * 8) = v;
}

// ---------------------------------------------------------------------------
// Phase 1: capture — BYTE-IDENTICAL to rounds 9..16 (deterministic LDS-weight
// form, HBM-bound ~65-75 us at 2 blocks/CU).
// ---------------------------------------------------------------------------
__global__ __launch_bounds__(256, 2) void capture_lds(
    const float* __restrict__ x,
    const short* __restrict__ wsw,
    const float* __restrict__ bc1, const float* __restrict__ bc2,
    float* __restrict__ capt)
{
  __shared__ bf16x8 wl[24 * 64];  // 24.5 KB fragment table

  const int tid  = threadIdx.x;
  const int lane = tid & 63;
  const int r    = lane & 15;   // tile-row (N dim)
  const int G    = lane >> 4;   // k-group
  const int wave = blockIdx.x * 4 + (tid >> 6);
  const int nwaves = gridDim.x * 4;

  for (int s = tid; s < 24 * 64; s += 256)
    wl[s] = ((const bf16x8*)wsw)[s];
  __syncthreads();

  f32x4 bias1[4], bias2[4];
#pragma unroll
  for (int m = 0; m < 4; ++m) {
    bias1[m] = *(const f32x4*)(bc1 + 16 * m + 4 * G);
    bias2[m] = *(const f32x4*)(bc2 + 16 * m + 4 * G);
  }

  for (int tile = wave; tile < (TT * BB) / 16; tile += nwaves) {
    asm volatile("" ::: "memory");

    const float* xrow = x + ((size_t)tile * 16 + r) * OBS;
    bf16x8 xa[4];
#pragma unroll
    for (int kk = 0; kk < 4; ++kk) {
      const float4 lo = *(const float4*)(xrow + kk * 32 + 8 * G);
      const float4 hi = *(const float4*)(xrow + kk * 32 + 8 * G + 4);
      bf16x8 f;
      f[0] = f2bf(lo.x); f[1] = f2bf(lo.y); f[2] = f2bf(lo.z); f[3] = f2bf(lo.w);
      f[4] = f2bf(hi.x); f[5] = f2bf(hi.y); f[6] = f2bf(hi.z); f[7] = f2bf(hi.w);
      xa[kk] = f;
    }

    float um[4][4];
#pragma unroll
    for (int m = 0; m < 4; ++m) {
      f32x4 acc = bias1[m];
#pragma unroll
      for (int kk = 0; kk < 4; ++kk)
        acc = __builtin_amdgcn_mfma_f32_16x16x32_bf16(wl[(m * 4 + kk) * 64 + lane],
                                                      xa[kk], acc, 0, 0, 0);
#pragma unroll
      for (int q = 0; q < 4; ++q) um[m][q] = fast_tanh(acc[q]);
    }

    bf16x8 b2[2];
#pragma unroll
    for (int kk = 0; kk < 2; ++kk) {
      bf16x8 f;
#pragma unroll
      for (int j = 0; j < 4; ++j) f[j]     = f2bf(um[2 * kk][j]);
#pragma unroll
      for (int j = 0; j < 4; ++j) f[4 + j] = f2bf(um[2 * kk + 1][j]);
      b2[kk] = f;
    }

    float* crow = capt + ((size_t)tile * 16 + r) * HID;
#pragma unroll
    for (int m = 0; m < 4; ++m) {
      f32x4 acc = bias2[m];
#pragma unroll
      for (int kk = 0; kk < 2; ++kk)
        acc = __builtin_amdgcn_mfma_f32_16x16x32_bf16(wl[(16 + m * 2 + kk) * 64 + lane],
                                                      b2[kk], acc, 0, 0, 0);
      float4 o;
      o.x = fast_tanh(acc[0]); o.y = fast_tanh(acc[1]);
      o.z = fast_tanh(acc[2]); o.w = fast_tanh(acc[3]);
      *(float4*)(crow + 16 * m + 4 * G) = o;
    }
  }
}

// ---------------------------------------------------------------------------
// Phase 2: recurrence — PRODUCER/CONSUMER wave split (new this round).
// Evidence r4/r14/r16: per-step stall ~1400 cyc scales with load batches and
// survives prefetch/pins/2-tile interleave — the backend's vmcnt placement on
// the consumer's global loads is the pathology. Fix: one block = 2 waves.
// Producer wave streams step t+1's contiguous (z1,a,g) slab (6 KB) into a
// double-buffered LDS ring; consumer wave runs the r15 h-chain with ZERO
// global loads in its loop (ds_read only — lgkmcnt scheduling is proven good,
// stores are fire-and-forget). One lgkm-barrier per step syncs the ring.
// LDS rows padded (68/36 f32) to bound bank conflicts. Weights in-loop-pinned
// (r15); cvt_pk packing (r12). Numerics identical (absmax unchanged).
// Grid: 256 blocks x 128 threads (1 block/CU; 2 waves on 2 SIMDs).
// ---------------------------------------------------------------------------
__global__ __launch_bounds__(128, 1) void recur_pc(
    const float* __restrict__ h0,
    const float* __restrict__ g,
    const float* __restrict__ a,
    const float* __restrict__ Wp1, const float* __restrict__ bp1,
    const float* __restrict__ Wp2, const float* __restrict__ bp2,
    const float* __restrict__ z1buf,
    float* __restrict__ outs, float* __restrict__ hlast)
{
  __shared__ float zS[2][16][68];  // z slot: 16 rows x 64 (+4 pad)
  __shared__ float aS[2][16][36];  // a slot: 16 rows x 32 (+4 pad)
  __shared__ float gS[2][16];

  const int tid  = threadIdx.x;
  const int lane = tid & 63;
  const int wid  = __builtin_amdgcn_readfirstlane(tid >> 6);
  const int row0 = blockIdx.x * 16;

  if (wid == 1) {
    // ================= PRODUCER =================
#define P_STAGE(t, p)                                                       \
    do {                                                                    \
      const size_t rb = (size_t)(t) * BB + row0;                            \
      const float* zp = z1buf + rb * HID;                                   \
      float4 zv[4];                                                         \
      _Pragma("unroll")                                                     \
      for (int i = 0; i < 4; ++i)                                           \
        zv[i] = *(const float4*)(zp + i * 256 + lane * 4);                  \
      const float* ap = a + rb * ACT;                                       \
      float4 av[2];                                                         \
      _Pragma("unroll")                                                     \
      for (int i = 0; i < 2; ++i)                                           \
        av[i] = *(const float4*)(ap + i * 256 + lane * 4);                  \
      float gv = 0.0f;                                                      \
      if (lane < 16) gv = g[rb + lane];                                     \
      _Pragma("unroll")                                                     \
      for (int i = 0; i < 4; ++i) {                                         \
        const int rr = i * 4 + (lane >> 4), cc = (lane & 15) * 4;           \
        *(float4*)&zS[p][rr][cc] = zv[i];                                   \
      }                                                                     \
      _Pragma("unroll")                                                     \
      for (int i = 0; i < 2; ++i) {                                         \
        const int rr = i * 8 + (lane >> 3), cc = (lane & 7) * 4;            \
        *(float4*)&aS[p][rr][cc] = av[i];                                   \
      }                                                                     \
      if (lane < 16) gS[p][lane] = gv;                                      \
    } while (0)

    P_STAGE(0, 0);
    lds_barrier();
    for (int t = 0; t < TT; ++t) {
      const int tn = (t + 1 < TT) ? (t + 1) : (TT - 1);  // clamp
      P_STAGE(tn, (t + 1) & 1);
      lds_barrier();
    }
  } else {
    // ================= CONSUMER =================
    const int r = lane & 15;
    const int G = lane >> 4;
    const int row = row0 + r;

    // weights gathered once; in-loop pin keeps them resident (r15)
    bf16x8 w1h[4][2], w2t[4][2], w1a[4];
#pragma unroll
    for (int m = 0; m < 4; ++m) {
#pragma unroll
      for (int kk = 0; kk < 2; ++kk) {
        bf16x8 f1, f2;
#pragma unroll
        for (int j = 0; j < 8; ++j) {
          const int k = (j < 4) ? (32 * kk + 4 * G + j)
                                : (32 * kk + 16 + 4 * G + (j - 4));
          f1[j] = f2bf(Wp1[k * HID + 16 * m + r]);
          f2[j] = f2bf(Wp2[k * HID + 16 * m + r]);
        }
        w1h[m][kk] = f1;
        w2t[m][kk] = f2;
      }
      bf16x8 fa;  // a-part, std map: k = HID + 8G + j
#pragma unroll
      for (int j = 0; j < 8; ++j)
        fa[j] = f2bf(Wp1[(HID + 8 * G + j) * HID + 16 * m + r]);
      w1a[m] = fa;
    }
    f32x4 bias1[4], bias2[4];
#pragma unroll
    for (int m = 0; m < 4; ++m) {
      bias1[m] = *(const f32x4*)(bp1 + 16 * m + 4 * G);
      bias2[m] = *(const f32x4*)(bp2 + 16 * m + 4 * G);
    }

    f32x4 hm[4];
#pragma unroll
    for (int m = 0; m < 4; ++m)
      hm[m] = *(const f32x4*)(h0 + (size_t)row * HID + 16 * m + 4 * G);
    bf16x8 hb0 = cvt8(hm[0], hm[1]);
    bf16x8 hb1 = cvt8(hm[2], hm[3]);

    lds_barrier();  // matches producer's initial-fill barrier

    for (int t = 0; t < TT; ++t) {
      // in-loop pin: weights/biases are loop-carried opaque values
#pragma unroll
      for (int m = 0; m < 4; ++m) {
        asm volatile("" : "+v"(w1h[m][0]), "+v"(w1h[m][1]));
        asm volatile("" : "+v"(w2t[m][0]), "+v"(w2t[m][1]));
        asm volatile("" : "+v"(w1a[m]));
        asm volatile("" : "+v"(bias1[m]), "+v"(bias2[m]));
      }

      const int p = t & 1;
      const f32x4 Z0 = *(const f32x4*)&zS[p][r][4 * G];
      const f32x4 Z1 = *(const f32x4*)&zS[p][r][16 + 4 * G];
      const f32x4 Z2 = *(const f32x4*)&zS[p][r][32 + 4 * G];
      const f32x4 Z3 = *(const f32x4*)&zS[p][r][48 + 4 * G];
      const float4 AL = *(const float4*)&aS[p][r][8 * G];
      const float4 AH = *(const float4*)&aS[p][r][8 * G + 4];
      const float GV = gS[p][r];

      const bf16x8 ab = cvt8f(AL, AH);
      f32x4 um[4];
#pragma unroll
      for (int m = 0; m < 4; ++m) {
        f32x4 acc = bias1[m];
        acc = __builtin_amdgcn_mfma_f32_16x16x32_bf16(w1h[m][0], hb0, acc, 0, 0, 0);
        acc = __builtin_amdgcn_mfma_f32_16x16x32_bf16(w1h[m][1], hb1, acc, 0, 0, 0);
        acc = __builtin_amdgcn_mfma_f32_16x16x32_bf16(w1a[m], ab, acc, 0, 0, 0);
        f32x4 u;
        u[0] = fast_tanh(acc[0]); u[1] = fast_tanh(acc[1]);
        u[2] = fast_tanh(acc[2]); u[3] = fast_tanh(acc[3]);
        um[m] = u;
      }
      const bf16x8 ub0 = cvt8(um[0], um[1]);
      const bf16x8 ub1 = cvt8(um[2], um[3]);
      const size_t ob = ((size_t)t * BB + row) * HID;
#pragma unroll
      for (int m = 0; m < 4; ++m) {
        f32x4 acc = bias2[m];
        acc = __builtin_amdgcn_mfma_f32_16x16x32_bf16(w2t[m][0], ub0, acc, 0, 0, 0);
        acc = __builtin_amdgcn_mfma_f32_16x16x32_bf16(w2t[m][1], ub1, acc, 0, 0, 0);
        const f32x4 zz = (m == 0) ? Z0 : (m == 1) ? Z1 : (m == 2) ? Z2 : Z3;
        f32x4 hn;
        hn[0] = fmaf(GV, fast_tanh(acc[0]) - zz[0], zz[0]);
        hn[1] = fmaf(GV, fast_tanh(acc[1]) - zz[1], zz[1]);
        hn[2] = fmaf(GV, fast_tanh(acc[2]) - zz[2], zz[2]);
        hn[3] = fmaf(GV, fast_tanh(acc[3]) - zz[3], zz[3]);
        hm[m] = hn;
        *(f32x4*)(outs + ob + 16 * m + 4 * G) = hn;
      }
      hb0 = cvt8(hm[0], hm[1]);
      hb1 = cvt8(hm[2], hm[3]);

      lds_barrier();
    }

#pragma unroll
    for (int m = 0; m < 4; ++m)
      *(f32x4*)(hlast + (size_t)row * HID + 16 * m + 4 * G) = hm[m];
  }
}

extern "C" void kernel_launch(void* const* d_in, const int* in_sizes, int n_in,
                              void* d_out, int out_size, void* d_ws, size_t ws_size,
                              hipStream_t stream) {
  const float* x   = (const float*)d_in[0];
  const float* h0  = (const float*)d_in[1];
  const float* g   = (const float*)d_in[2];
  const float* a   = (const float*)d_in[3];
  const float* Wc1 = (const float*)d_in[4];
  const float* bc1 = (const float*)d_in[5];
  const float* Wc2 = (const float*)d_in[6];
  const float* bc2 = (const float*)d_in[7];
  const float* Wp1 = (const float*)d_in[8];
  const float* bp1 = (const float*)d_in[9];
  const float* Wp2 = (const float*)d_in[10];
  const float* bp2 = (const float*)d_in[11];

  float* out   = (float*)d_out;
  float* outs  = out;                                   // [T,B,H]
  float* hlast = out + (size_t)TT * BB * HID;           // [1,B,H]
  float* capt  = hlast + (size_t)BB * HID;              // [T,B,H]
  short* wsw   = (short*)d_ws;                          // 44 KB fragment buffer

  prep_weights<<<dim3(11), dim3(256), 0, stream>>>(Wc1, Wc2, Wp1, Wp2, wsw);
  capture_lds<<<dim3(2048), dim3(256), 0, stream>>>(x, wsw, bc1, bc2, capt);
  recur_pc<<<dim3(BB / 16), dim3(128), 0, stream>>>(h0, g, a, Wp1, bp1, Wp2, bp2,
                                                    capt, outs, hlast);
}